// Round 1
// baseline (309.973 us; speedup 1.0000x reference)
//
#include <hip/hip_runtime.h>
#include <stdint.h>

// ---------------- problem constants ----------------
#define HW_      102400          // 320*320
#define WIDTH_   320
#define C_       256
#define N_       1024
#define P_       2               // pairs
#define CHUNKS_  100             // HW chunks per (pair, n-block)
#define CHUNK_PX 1024
#define ITERS_   16              // 16 * 64 px = 1024 px per chunk
#define NB_      4               // n-blocks of 256 keypoints
#define K2_      144.269504088896340f   // 100 / ln(2): exp(100*x) = exp2(K2*x)

typedef __attribute__((ext_vector_type(8))) short bf16x8;
typedef __attribute__((ext_vector_type(4))) float f32x4;

// ws layout (bytes):
//   invnorm : [0, 819200)                      2*102400 f32
//   tgt bf16: [819200, 1867776)                2*1024*256 bf16, [p][n][c]
//   partials: [1867776, 8421376)               2*200*1024 float4 (M,S,U,V)
#define WS_INV_OFF  0
#define WS_TGT_OFF  819200
#define WS_PAR_OFF  1867776

__device__ __forceinline__ uint32_t f2bf(float x) {
  // round-to-nearest-even f32 -> bf16 (finite inputs only)
  uint32_t u = __builtin_bit_cast(uint32_t, x);
  return (u + 0x7FFFu + ((u >> 16) & 1u)) >> 16;
}
__device__ __forceinline__ uint32_t packbf(float a, float b) {
  return f2bf(a) | (f2bf(b) << 16);
}
__device__ __forceinline__ float fexp2(float x) {
  return __builtin_amdgcn_exp2f(x);
}

// ---------------- kernel 1: per-pixel inverse L2 norm of src planes ----------------
__global__ void k_invnorm(const float* __restrict__ dense, float* __restrict__ invn) {
  const int p  = blockIdx.y;
  const int m4 = (blockIdx.x * blockDim.x + threadIdx.x) * 4;   // 4 px / thread
  const float* plane = dense + (size_t)(p * 2) * C_ * HW_;      // src ids = 0, 2
  float sx = 0.f, sy = 0.f, sz = 0.f, sw = 0.f;
  #pragma unroll 4
  for (int c = 0; c < C_; ++c) {
    float4 v = *(const float4*)(plane + (size_t)c * HW_ + m4);
    sx += v.x * v.x; sy += v.y * v.y; sz += v.z * v.z; sw += v.w * v.w;
  }
  float4 r;
  r.x = 1.f / fmaxf(sqrtf(sx), 1e-12f);
  r.y = 1.f / fmaxf(sqrtf(sy), 1e-12f);
  r.z = 1.f / fmaxf(sqrtf(sz), 1e-12f);
  r.w = 1.f / fmaxf(sqrtf(sw), 1e-12f);
  *(float4*)(invn + (size_t)p * HW_ + m4) = r;
}

// ---------------- kernel 2: normalize tgt keypoint descs -> bf16 [p][n][c]; copy weights ----------------
__global__ void k_tgt(const float* __restrict__ kdesc, const float* __restrict__ kscores,
                      uint16_t* __restrict__ tgt, float* __restrict__ out) {
  const int t = blockIdx.x * blockDim.x + threadIdx.x;   // 0..2047
  const int p = t >> 10, n = t & 1023;
  const float* src = kdesc + (size_t)(p * 2 + 1) * C_ * N_;   // tgt ids = 1, 3
  float s = 0.f;
  #pragma unroll 4
  for (int c = 0; c < C_; ++c) { const float v = src[c * N_ + n]; s += v * v; }
  const float inv = 1.f / fmaxf(sqrtf(s), 1e-12f);
  uint16_t* dst = tgt + (size_t)t * C_;
  #pragma unroll 4
  for (int c = 0; c < C_; ++c) dst[c] = (uint16_t)f2bf(src[c * N_ + n] * inv);
  // match_weights = keypoint_scores[tgt_ids] -> out[4096 + p*1024 + n]
  out[4096 + t] = kscores[(p * 2 + 1) * N_ + n];
}

// ---------------- kernel 3: fused QK^T + online softmax + soft-argmax partials ----------------
// block: 512 thr (8 waves as 2(m) x 4(n)); per block: 1 pair, 256 keypoints, 1024 px chunk
// grid:  P_ * NB_ * CHUNKS_ = 800
__global__ __launch_bounds__(512, 2)
void k_main(const float* __restrict__ dense, const float* __restrict__ invn,
            const uint16_t* __restrict__ tgt, float4* __restrict__ partials) {
  __shared__ uint32_t lds[64 * 128];   // 64 px rows x 256 bf16 (packed u32), XOR-swizzled

  const int bid   = blockIdx.x;
  const int chunk = bid % CHUNKS_;
  const int nb    = (bid / CHUNKS_) % NB_;
  const int p     = bid / (CHUNKS_ * NB_);

  const int t    = threadIdx.x;
  const int lane = t & 63;
  const int w    = t >> 6;
  const int l15  = lane & 15;
  const int g    = lane >> 4;
  const int h    = w & 1;    // m-half: 32 px
  const int q    = w >> 1;   // n-quarter: 64 keypoints

  const float* plane = dense + (size_t)(p * 2) * C_ * HW_;
  const float* invp  = invn + (size_t)p * HW_;

  // ---- B fragments (tgt, [n][c] bf16): lane holds n = l15, k-chunk c = k*32 + g*8 .. +7 ----
  bf16x8 Bf[4][8];
  const int nbase = nb * 256 + q * 64;
  #pragma unroll
  for (int j = 0; j < 4; ++j) {
    const uint16_t* tp = tgt + (size_t)(p * N_ + nbase + j * 16 + l15) * C_ + g * 8;
    #pragma unroll
    for (int k = 0; k < 8; ++k) Bf[j][k] = *(const bf16x8*)(tp + k * 32);
  }

  // per-lane online-softmax state, one slot per ntile j (n = nbase + j*16 + l15)
  float stM[4], stS[4], stU[4], stV[4];
  #pragma unroll
  for (int j = 0; j < 4; ++j) { stM[j] = -3e38f; stS[j] = 0.f; stU[j] = 0.f; stV[j] = 0.f; }

  // staging mapping: thread t loads 8 channel rows (c8..c8+7) x 4 px (mi..mi+3)
  const int mi   = (t & 15) * 4;
  const int c8   = (t >> 4) * 8;
  const int wcol = (t >> 4) * 4;           // dword col within LDS row
  const int px0  = chunk * CHUNK_PX;

  const int row0 = h * 32 + l15;           // A-frag row, subtile 0 (subtile 1 = +16)
  const int swr  = (row0 & 7) << 2;        // read swizzle (same for row0+16)

  for (int iter = 0; iter < ITERS_; ++iter) {
    // ---- issue global loads early (latency overlaps previous compute via the barrier) ----
    const int px = px0 + iter * 64 + mi;
    float fva[8][4];
    #pragma unroll
    for (int j = 0; j < 8; ++j) {
      float4 v = *(const float4*)(plane + (size_t)(c8 + j) * HW_ + px);
      fva[j][0] = v.x; fva[j][1] = v.y; fva[j][2] = v.z; fva[j][3] = v.w;
    }
    float4 ivv = *(const float4*)(invp + px);
    float iva[4] = {ivv.x, ivv.y, ivv.z, ivv.w};

    __syncthreads();   // previous iter done reading LDS

    // ---- normalize, pack bf16 pairs, b128 LDS writes (bank-floor via XOR swizzle) ----
    #pragma unroll
    for (int i = 0; i < 4; ++i) {
      const int row = mi + i;
      uint4 wv;
      wv.x = packbf(fva[0][i] * iva[i], fva[1][i] * iva[i]);
      wv.y = packbf(fva[2][i] * iva[i], fva[3][i] * iva[i]);
      wv.z = packbf(fva[4][i] * iva[i], fva[5][i] * iva[i]);
      wv.w = packbf(fva[6][i] * iva[i], fva[7][i] * iva[i]);
      *(uint4*)&lds[row * 128 + (wcol ^ ((row & 7) << 2))] = wv;
    }
    __syncthreads();

    // ---- MFMA: S^T tile = src(m,k) x tgt(k,n); acc[j][s] = 16px x 16n ----
    f32x4 acc[4][2];
    #pragma unroll
    for (int j = 0; j < 4; ++j) {
      acc[j][0] = (f32x4){0.f, 0.f, 0.f, 0.f};
      acc[j][1] = (f32x4){0.f, 0.f, 0.f, 0.f};
    }
    #pragma unroll
    for (int k = 0; k < 8; ++k) {
      const int col = k * 16 + g * 4;
      bf16x8 a0 = *(const bf16x8*)&lds[row0 * 128 + (col ^ swr)];
      bf16x8 a1 = *(const bf16x8*)&lds[(row0 + 16) * 128 + (col ^ swr)];
      #pragma unroll
      for (int j = 0; j < 4; ++j) {
        acc[j][0] = __builtin_amdgcn_mfma_f32_16x16x32_bf16(a0, Bf[j][k], acc[j][0], 0, 0, 0);
        acc[j][1] = __builtin_amdgcn_mfma_f32_16x16x32_bf16(a1, Bf[j][k], acc[j][1], 0, 0, 0);
      }
    }

    // ---- pixel coordinates for this lane's 8 rows: m = mb + s*16 + r ----
    const float mb = (float)(px0 + iter * 64 + h * 32 + g * 4);
    float uarr[8], varr[8];
    #pragma unroll
    for (int s = 0; s < 2; ++s) {
      #pragma unroll
      for (int r = 0; r < 4; ++r) {
        const float mf = mb + (float)(s * 16 + r);
        const float vf = floorf((mf + 0.5f) * (1.0f / 320.0f));
        varr[s * 4 + r] = vf;
        uarr[s * 4 + r] = mf - vf * 320.0f;
      }
    }

    // ---- per-lane online softmax update (no cross-lane ops) ----
    #pragma unroll
    for (int j = 0; j < 4; ++j) {
      float a[8];
      a[0] = acc[j][0][0]; a[1] = acc[j][0][1]; a[2] = acc[j][0][2]; a[3] = acc[j][0][3];
      a[4] = acc[j][1][0]; a[5] = acc[j][1][1]; a[6] = acc[j][1][2]; a[7] = acc[j][1][3];
      const float mx = fmaxf(fmaxf(fmaxf(a[0], a[1]), fmaxf(a[2], a[3])),
                             fmaxf(fmaxf(a[4], a[5]), fmaxf(a[6], a[7])));
      const float Mn  = fmaxf(stM[j], mx);
      const float fsc = fexp2(K2_ * (stM[j] - Mn));
      float S = stS[j] * fsc, U = stU[j] * fsc, V = stV[j] * fsc;
      #pragma unroll
      for (int e = 0; e < 8; ++e) {
        const float ev = fexp2(K2_ * (a[e] - Mn));
        S += ev; U += ev * uarr[e]; V += ev * varr[e];
      }
      stM[j] = Mn; stS[j] = S; stU[j] = U; stV[j] = V;
    }
  }

  // ---- merge the 4 lane-groups (disjoint m subsets, same n) via LSE-merge ----
  #pragma unroll
  for (int j = 0; j < 4; ++j) {
    float M = stM[j], S = stS[j], U = stU[j], V = stV[j];
    for (int mask = 16; mask <= 32; mask <<= 1) {
      const float oM = __shfl_xor(M, mask, 64);
      const float oS = __shfl_xor(S, mask, 64);
      const float oU = __shfl_xor(U, mask, 64);
      const float oV = __shfl_xor(V, mask, 64);
      const float Mn = fmaxf(M, oM);
      const float f1 = fexp2(K2_ * (M - Mn));
      const float f2 = fexp2(K2_ * (oM - Mn));
      S = S * f1 + oS * f2;
      U = U * f1 + oU * f2;
      V = V * f1 + oV * f2;
      M = Mn;
    }
    if (lane < 16) {
      const int n = nbase + j * 16 + l15;
      partials[(size_t)(p * 2 * CHUNKS_ + chunk * 2 + h) * N_ + n] = make_float4(M, S, U, V);
    }
  }
}

// ---------------- kernel 4: LSE-reduce 200 partials per (p, n) -> coords; ids ----------------
__global__ void k_final(const float4* __restrict__ partials, float* __restrict__ out) {
  const int t = blockIdx.x * blockDim.x + threadIdx.x;   // 0..2047
  const int p = t >> 10, n = t & 1023;
  float M = -3e38f, S = 0.f, U = 0.f, V = 0.f;
  for (int s = 0; s < 2 * CHUNKS_; ++s) {
    const float4 v = partials[(size_t)(p * 2 * CHUNKS_ + s) * N_ + n];
    const float Mn = fmaxf(M, v.x);
    const float f1 = fexp2(K2_ * (M - Mn));
    const float f2 = fexp2(K2_ * (v.x - Mn));
    S = S * f1 + v.y * f2;
    U = U * f1 + v.z * f2;
    V = V * f1 + v.w * f2;
    M = Mn;
  }
  out[(size_t)(p * N_ + n) * 2 + 0] = U / S;   // u = m % 320
  out[(size_t)(p * N_ + n) * 2 + 1] = V / S;   // v = m / 320
  if (t < 4) {
    const float ids[4] = {1.f, 3.f, 0.f, 2.f};  // tgt_ids then src_ids
    out[6144 + t] = ids[t];
  }
}

// ---------------- host launch ----------------
extern "C" void kernel_launch(void* const* d_in, const int* in_sizes, int n_in,
                              void* d_out, int out_size, void* d_ws, size_t ws_size,
                              hipStream_t stream) {
  const float* kscores = (const float*)d_in[0];   // (4,1,1024)
  const float* kdesc   = (const float*)d_in[1];   // (4,256,1024)
  const float* dense   = (const float*)d_in[2];   // (4,256,320,320)
  // d_in[3] keypoint_coords is unused by the reference.
  float* out = (float*)d_out;

  char* ws = (char*)d_ws;                          // needs ~8.5 MB
  float*    invn = (float*)(ws + WS_INV_OFF);
  uint16_t* tgt  = (uint16_t*)(ws + WS_TGT_OFF);
  float4*   par  = (float4*)(ws + WS_PAR_OFF);

  k_invnorm<<<dim3(HW_ / (256 * 4), P_), 256, 0, stream>>>(dense, invn);
  k_tgt<<<(P_ * N_) / 256, 256, 0, stream>>>(kdesc, kscores, tgt, out);
  k_main<<<P_ * NB_ * CHUNKS_, 512, 0, stream>>>(dense, invn, tgt, par);
  k_final<<<(P_ * N_) / 256, 256, 0, stream>>>(par, out);
}

// Round 2
// 186.740 us; speedup vs baseline: 1.6599x; 1.6599x over previous
//
#include <hip/hip_runtime.h>
#include <stdint.h>

// ---------------- problem constants ----------------
#define HW_      102400          // 320*320
#define WIDTH_   320
#define C_       256
#define N_       1024
#define P_       2               // pairs
#define CHUNKS_  64              // HW chunks per (pair, n-block)
#define CHUNK_PX 1600            // 5 rows of 320 -> chunks are row-aligned
#define ITERS_   25              // 25 * 64 px = 1600 px per chunk
#define NB_      4               // n-blocks of 256 keypoints
#define K2_      144.269504088896340f   // 100 / ln(2)
#define MOFF_    (-72.134752044448170f) // -K2_ * 0.5  (fixed softmax max = 0.5)

typedef __attribute__((ext_vector_type(8))) short bf16x8;
typedef __attribute__((ext_vector_type(4))) float f32x4;

// ws layout (bytes):
//   invnorm : [0, 819200)                  2*102400 f32
//   tgt bf16: [819200, 1867776)            2*1024*256 bf16, [p][n][c]
//   partials: [1867776, ~6.1MB)            2*128*1024 float4 (S,U,V,-)
#define WS_INV_OFF  0
#define WS_TGT_OFF  819200
#define WS_PAR_OFF  1867776

__device__ __forceinline__ uint32_t packbf(float a, float b) {
  // D[15:0] = bf16(a), D[31:16] = bf16(b), RNE
  uint32_t r;
  asm("v_cvt_pk_bf16_f32 %0, %1, %2" : "=v"(r) : "v"(a), "v"(b));
  return r;
}
__device__ __forceinline__ float fexp2(float x) {
  return __builtin_amdgcn_exp2f(x);
}

// ---------------- kernel 1: fused (a) per-pixel inv L2 norm of src planes,
// ----------------           (b) normalize tgt keypoint descs -> bf16, copy weights
__global__ __launch_bounds__(256)
void k_pre(const float* __restrict__ dense, const float* __restrict__ kdesc,
           const float* __restrict__ kscores, float* __restrict__ invn,
           uint16_t* __restrict__ tgt, float* __restrict__ out) {
  const int bid = blockIdx.x;
  if (bid < 800) {
    // ---- per-pixel inverse norm: 1 px / thread, 800 blocks -> ~12 waves/CU ----
    const int p  = bid / 400;
    const int px = (bid % 400) * 256 + threadIdx.x;
    const float* plane = dense + (size_t)(p * 2) * C_ * HW_ + px;   // src ids 0,2
    float s = 0.f;
    #pragma unroll 8
    for (int c = 0; c < C_; ++c) { const float v = plane[(size_t)c * HW_]; s = fmaf(v, v, s); }
    invn[p * HW_ + px] = 1.f / fmaxf(sqrtf(s), 1e-12f);
  } else {
    // ---- tgt keypoint descriptors ----
    const int t = (bid - 800) * 256 + threadIdx.x;   // 0..2047
    const int p = t >> 10, n = t & 1023;
    const float* src = kdesc + (size_t)(p * 2 + 1) * C_ * N_ + n;   // tgt ids 1,3
    float s = 0.f;
    #pragma unroll 16
    for (int c = 0; c < C_; ++c) { const float v = src[c * N_]; s = fmaf(v, v, s); }
    const float inv = 1.f / fmaxf(sqrtf(s), 1e-12f);
    uint32_t* dst = (uint32_t*)(tgt + (size_t)t * C_);   // 256B-aligned row
    #pragma unroll 4
    for (int c8 = 0; c8 < C_; c8 += 8) {
      uint4 wv;
      wv.x = packbf(src[(c8 + 0) * N_] * inv, src[(c8 + 1) * N_] * inv);
      wv.y = packbf(src[(c8 + 2) * N_] * inv, src[(c8 + 3) * N_] * inv);
      wv.z = packbf(src[(c8 + 4) * N_] * inv, src[(c8 + 5) * N_] * inv);
      wv.w = packbf(src[(c8 + 6) * N_] * inv, src[(c8 + 7) * N_] * inv);
      *(uint4*)&dst[c8 / 2] = wv;
    }
    out[4096 + t] = kscores[(p * 2 + 1) * N_ + n];   // match_weights
  }
}

// ---------------- kernel 2: fused QK^T + fixed-max softmax + soft-argmax partials ----------------
// block: 512 thr (8 waves as 2(m) x 4(n)); grid: P_ * NB_ * CHUNKS_ = 512 (exactly 2/CU)
// single-barrier double-buffered pipeline: loads(t+1) || mfma+softmax(t) ; write(t+1) ; barrier
__global__ __launch_bounds__(512, 2)
void k_main(const float* __restrict__ dense, const float* __restrict__ invn,
            const uint16_t* __restrict__ tgt, float4* __restrict__ partials) {
  __shared__ uint32_t lds[2 * 64 * 128];   // 2 bufs x (64 px rows x 256 bf16), XOR-swizzled

  const int bid   = blockIdx.x;
  const int chunk = bid % CHUNKS_;
  const int nb    = (bid / CHUNKS_) % NB_;
  const int p     = bid / (CHUNKS_ * NB_);

  const int t    = threadIdx.x;
  const int lane = t & 63;
  const int w    = t >> 6;
  const int l15  = lane & 15;
  const int g    = lane >> 4;
  const int h    = w & 1;    // m-half: 32 px
  const int q    = w >> 1;   // n-quarter: 64 keypoints

  const float* plane = dense + (size_t)(p * 2) * C_ * HW_;
  const float* invp  = invn + (size_t)p * HW_;

  // ---- B fragments (tgt, [n][c] bf16): lane n = l15, k-slice c = k*32 + g*8 .. +7 ----
  bf16x8 Bf[4][8];
  const int nbase = nb * 256 + q * 64;
  #pragma unroll
  for (int j = 0; j < 4; ++j) {
    const uint16_t* tp = tgt + (size_t)(p * N_ + nbase + j * 16 + l15) * C_ + g * 8;
    #pragma unroll
    for (int k = 0; k < 8; ++k) Bf[j][k] = *(const bf16x8*)(tp + k * 32);
  }

  // fixed-max softmax state (max pinned at 0.5; cosine logits <= ~1.02, no overflow/underflow)
  float stS[4], stU[4], stV[4];
  #pragma unroll
  for (int j = 0; j < 4; ++j) { stS[j] = 0.f; stU[j] = 0.f; stV[j] = 0.f; }

  // staging: thread t loads 8 channel rows (c8..c8+7) x 4 px (mi..mi+3)
  const int mi   = (t & 15) * 4;
  const int c8   = (t >> 4) * 8;
  const int wcol = (t >> 4) * 4;           // dword col within LDS row
  const int px0  = chunk * CHUNK_PX;

  const int row0 = h * 32 + l15;           // A-frag row (subtile 1 = +16)
  const int swr  = (row0 & 7) << 2;        // read swizzle

  uint32_t* bufR = lds;                    // read buffer
  uint32_t* bufW = lds + 64 * 128;         // write buffer

  float fva[8][4];
  float iva[4];

  // ---- prologue: load iter 0, pack+write bufR ----
  {
    const int px = px0 + mi;
    #pragma unroll
    for (int j = 0; j < 8; ++j) {
      float4 v = *(const float4*)(plane + (size_t)(c8 + j) * HW_ + px);
      fva[j][0] = v.x; fva[j][1] = v.y; fva[j][2] = v.z; fva[j][3] = v.w;
    }
    float4 ivv = *(const float4*)(invp + px);
    iva[0] = ivv.x; iva[1] = ivv.y; iva[2] = ivv.z; iva[3] = ivv.w;
    #pragma unroll
    for (int i = 0; i < 4; ++i) {
      const int row = mi + i;
      uint4 wv;
      wv.x = packbf(fva[0][i] * iva[i], fva[1][i] * iva[i]);
      wv.y = packbf(fva[2][i] * iva[i], fva[3][i] * iva[i]);
      wv.z = packbf(fva[4][i] * iva[i], fva[5][i] * iva[i]);
      wv.w = packbf(fva[6][i] * iva[i], fva[7][i] * iva[i]);
      *(uint4*)&bufR[row * 128 + (wcol ^ ((row & 7) << 2))] = wv;
    }
  }
  __syncthreads();

  for (int iter = 0; iter < ITERS_; ++iter) {
    const bool more = (iter + 1 < ITERS_);

    // ---- issue next tile's global loads (latency hides under MFMA below) ----
    if (more) {
      const int px = px0 + (iter + 1) * 64 + mi;
      #pragma unroll
      for (int j = 0; j < 8; ++j) {
        float4 v = *(const float4*)(plane + (size_t)(c8 + j) * HW_ + px);
        fva[j][0] = v.x; fva[j][1] = v.y; fva[j][2] = v.z; fva[j][3] = v.w;
      }
      float4 ivv = *(const float4*)(invp + px);
      iva[0] = ivv.x; iva[1] = ivv.y; iva[2] = ivv.z; iva[3] = ivv.w;
    }

    // ---- MFMA from bufR: acc[j][s] = 16px x 16n ----
    f32x4 acc[4][2];
    #pragma unroll
    for (int j = 0; j < 4; ++j) {
      acc[j][0] = (f32x4){0.f, 0.f, 0.f, 0.f};
      acc[j][1] = (f32x4){0.f, 0.f, 0.f, 0.f};
    }
    #pragma unroll
    for (int k = 0; k < 8; ++k) {
      const int col = (k * 16 + g * 4) ^ swr;
      bf16x8 a0 = *(const bf16x8*)&bufR[row0 * 128 + col];
      bf16x8 a1 = *(const bf16x8*)&bufR[(row0 + 16) * 128 + col];
      #pragma unroll
      for (int j = 0; j < 4; ++j) {
        acc[j][0] = __builtin_amdgcn_mfma_f32_16x16x32_bf16(a0, Bf[j][k], acc[j][0], 0, 0, 0);
        acc[j][1] = __builtin_amdgcn_mfma_f32_16x16x32_bf16(a1, Bf[j][k], acc[j][1], 0, 0, 0);
      }
    }

    // ---- fixed-max softmax + soft-argmax accumulation ----
    // element (s,e) is chunk-local pixel r = iter*64 + h*32 + s*16 + g*4 + e
    const int rb = iter * 64 + h * 32 + g * 4;
    #pragma unroll
    for (int s = 0; s < 2; ++s) {
      #pragma unroll
      for (int e = 0; e < 4; ++e) {
        const int r  = rb + s * 16 + e;            // < 1600
        const int vl = (r * 6554) >> 21;           // == r / 320 for r < 16000
        const float vf = (float)(chunk * 5 + vl);  // global row
        const float uf = (float)(r - vl * 320);    // global col
        #pragma unroll
        for (int j = 0; j < 4; ++j) {
          const float ev = fexp2(fmaf(K2_, acc[j][s][e], MOFF_));
          stS[j] += ev;
          stU[j] = fmaf(ev, uf, stU[j]);
          stV[j] = fmaf(ev, vf, stV[j]);
        }
      }
    }

    // ---- pack + write next tile into bufW (vmcnt wait inserted by compiler) ----
    if (more) {
      #pragma unroll
      for (int i = 0; i < 4; ++i) {
        const int row = mi + i;
        uint4 wv;
        wv.x = packbf(fva[0][i] * iva[i], fva[1][i] * iva[i]);
        wv.y = packbf(fva[2][i] * iva[i], fva[3][i] * iva[i]);
        wv.z = packbf(fva[4][i] * iva[i], fva[5][i] * iva[i]);
        wv.w = packbf(fva[6][i] * iva[i], fva[7][i] * iva[i]);
        *(uint4*)&bufW[row * 128 + (wcol ^ ((row & 7) << 2))] = wv;
      }
    }
    __syncthreads();
    uint32_t* tmp = bufR; bufR = bufW; bufW = tmp;
  }

  // ---- merge the 4 lane-groups (disjoint px subsets, same n): plain sums ----
  #pragma unroll
  for (int j = 0; j < 4; ++j) {
    float S = stS[j], U = stU[j], V = stV[j];
    S += __shfl_xor(S, 16, 64); U += __shfl_xor(U, 16, 64); V += __shfl_xor(V, 16, 64);
    S += __shfl_xor(S, 32, 64); U += __shfl_xor(U, 32, 64); V += __shfl_xor(V, 32, 64);
    if (lane < 16) {
      const int n = nbase + j * 16 + l15;
      partials[((size_t)(p * CHUNKS_ + chunk) * 2 + h) * N_ + n] = make_float4(S, U, V, 0.f);
    }
  }
}

// ---------------- kernel 3: sum 128 partials per (p, n) -> coords; ids ----------------
__global__ void k_final(const float4* __restrict__ partials, float* __restrict__ out) {
  const int t = blockIdx.x * blockDim.x + threadIdx.x;   // 0..2047
  const int p = t >> 10, n = t & 1023;
  float S = 0.f, U = 0.f, V = 0.f;
  #pragma unroll 4
  for (int s = 0; s < 2 * CHUNKS_; ++s) {
    const float4 v = partials[((size_t)p * 2 * CHUNKS_ + s) * N_ + n];
    S += v.x; U += v.y; V += v.z;
  }
  out[(size_t)(p * N_ + n) * 2 + 0] = U / S;   // u
  out[(size_t)(p * N_ + n) * 2 + 1] = V / S;   // v
  if (t < 4) {
    const float ids[4] = {1.f, 3.f, 0.f, 2.f};  // tgt_ids then src_ids
    out[6144 + t] = ids[t];
  }
}

// ---------------- host launch ----------------
extern "C" void kernel_launch(void* const* d_in, const int* in_sizes, int n_in,
                              void* d_out, int out_size, void* d_ws, size_t ws_size,
                              hipStream_t stream) {
  const float* kscores = (const float*)d_in[0];   // (4,1,1024)
  const float* kdesc   = (const float*)d_in[1];   // (4,256,1024)
  const float* dense   = (const float*)d_in[2];   // (4,256,320,320)
  float* out = (float*)d_out;

  char* ws = (char*)d_ws;
  float*    invn = (float*)(ws + WS_INV_OFF);
  uint16_t* tgt  = (uint16_t*)(ws + WS_TGT_OFF);
  float4*   par  = (float4*)(ws + WS_PAR_OFF);

  k_pre<<<808, 256, 0, stream>>>(dense, kdesc, kscores, invn, tgt, out);
  k_main<<<P_ * NB_ * CHUNKS_, 512, 0, stream>>>(dense, invn, tgt, par);
  k_final<<<(P_ * N_) / 256, 256, 0, stream>>>(par, out);
}